// Round 4
// baseline (274.552 us; speedup 1.0000x reference)
//
#include <hip/hip_runtime.h>
#include <math.h>

// Problem constants
#define BB   64
#define FC   24
#define NN   1000
#define HID  64
#define EMBD 32
#define TT   48
#define FF   8
#define INSZ 33

// Decoder tiling
#define CPB  32     // cells per block, split into 2 groups of 16
#define TPB  256    // 4 waves
#define AST  72     // Abuf stride in bf16 elems (16B-aligned rows)
#define XST  40     // Xtile stride in bf16 elems (80B rows, 16B-aligned)

#define NL2E (-1.4426950408889634f)   // -log2(e): folded into r,z gate weights
#define TL2E ( 2.8853900817779268f)   // 2*log2(e): folded into n gate weights

typedef __attribute__((ext_vector_type(8))) short bf16x8;
typedef __attribute__((ext_vector_type(4))) float f32x4;

static __device__ __forceinline__ unsigned short f2bf(float f) {
    unsigned u = __builtin_bit_cast(unsigned, f);
    u += 0x7FFFu + ((u >> 16) & 1u);      // RNE
    return (unsigned short)(u >> 16);
}
// packed RNE f32->bf16: lo16 = bf16(a), hi16 = bf16(b)  (order verified R2)
static __device__ __forceinline__ unsigned cvt_pk_bf16(float a, float b) {
    unsigned r;
    asm("v_cvt_pk_bf16_f32 %0, %1, %2" : "=v"(r) : "v"(a), "v"(b));
    return r;
}
static __device__ __forceinline__ bf16x8 mk_bf8(float4 lo, float4 hi, float s) {
    union { unsigned u[4]; bf16x8 v; } r;
    r.u[0] = cvt_pk_bf16(lo.x * s, lo.y * s);
    r.u[1] = cvt_pk_bf16(lo.z * s, lo.w * s);
    r.u[2] = cvt_pk_bf16(hi.x * s, hi.y * s);
    r.u[3] = cvt_pk_bf16(hi.z * s, hi.w * s);
    return r.v;
}

// Workgroup barrier draining ONLY lgkmcnt (LDS). Safe: global ops in
// flight are register loads (private) and `out` stores (never re-read).
static __device__ __forceinline__ void lds_barrier() {
    __builtin_amdgcn_sched_barrier(0);
    asm volatile("s_waitcnt lgkmcnt(0)" ::: "memory");
    __builtin_amdgcn_s_barrier();
    __builtin_amdgcn_sched_barrier(0);
}

__global__ __launch_bounds__(TPB) __attribute__((amdgpu_waves_per_eu(3)))
void gru_decoder(
    const float* __restrict__ X,    // [B][TT][N][F]
    const float* __restrict__ hn0,  // [B*N][HID]
    const float* __restrict__ xn,   // [B][N][1]
    const float* __restrict__ emb,  // [NEMB][EMBD]
    const float* __restrict__ Wih,  // [3*HID][INSZ]
    const float* __restrict__ Whh,  // [3*HID][HID]
    const float* __restrict__ bih,  // [3*HID]
    const float* __restrict__ bhh,  // [3*HID]
    const float* __restrict__ Wout, // [1][HID]
    const float* __restrict__ bout, // [1]
    float* __restrict__ out)        // [B][FC][N][1]
{
    __shared__ __align__(16) unsigned short Abuf[CPB * AST];     // 4608 B
    __shared__ __align__(16) unsigned short Xt[2][CPB * XST];    // 5120 B
    __shared__ int   idxbuf[FC * CPB];                           // 3072 B
    __shared__ float xbuf[CPB];

    const int tid  = threadIdx.x;
    const int lane = tid & 63;
    const int g    = tid >> 6;         // wave 0..3, owns gate-cols g*16..g*16+15
    const int quad = lane >> 4;
    const int l15  = lane & 15;
    const int jcol = g * 16 + l15;
    const int rowb = quad * 4;
    const int cell0 = blockIdx.x * CPB;

    // ---- stage idx for all FC steps ----
    for (int e = tid; e < FC * CPB; e += TPB) {
        int t = e >> 5, m = e & 31;
        int cell = cell0 + m;
        int b = cell / NN, n = cell - b * NN;
        idxbuf[t * CPB + m] = (int)X[(((size_t)b * TT + t) * NN + n) * FF + 7];
    }
    if (tid < CPB) xbuf[tid] = xn[cell0 + tid];

    // ---- persistent B fragments: Whh^T with log2e prescale (24 VGPRs) ----
    bf16x8 Bf[3][2];
    #pragma unroll
    for (int gate = 0; gate < 3; ++gate) {
        const float s = (gate < 2) ? NL2E : TL2E;
        #pragma unroll
        for (int ks = 0; ks < 2; ++ks) {
            const float* src = Whh + (size_t)(gate * HID + jcol) * HID + ks * 32 + quad * 8;
            Bf[gate][ks] = mk_bf8(*(const float4*)src, *(const float4*)(src + 4), s);
        }
    }
    // ---- Wih embedding-part fragments (cols 1..32), prescaled (12 VGPRs) ----
    bf16x8 BX[3];
    #pragma unroll
    for (int gate = 0; gate < 3; ++gate) {
        const float s = (gate < 2) ? NL2E : TL2E;
        const float* src = Wih + (size_t)(gate * HID + jcol) * INSZ + 1 + quad * 8;
        union { unsigned u[4]; bf16x8 v; } f;
        #pragma unroll
        for (int p = 0; p < 4; ++p)
            f.u[p] = cvt_pk_bf16(src[2 * p] * s, src[2 * p + 1] * s);
        BX[gate] = f.v;
    }

    const float w0r2 = NL2E * Wih[(size_t)jcol * INSZ];
    const float w0z2 = NL2E * Wih[(size_t)(HID + jcol) * INSZ];
    const float w0n2 = TL2E * Wih[(size_t)(2 * HID + jcol) * INSZ];
    const float br2  = NL2E * (bih[jcol] + bhh[jcol]);
    const float bz2  = NL2E * (bih[HID + jcol] + bhh[HID + jcol]);
    const float bni2 = TL2E * bih[2 * HID + jcol];
    const float bhn2 = TL2E * bhh[2 * HID + jcol];
    const float bout0 = bout[0];

    // ---- out-dot role: (wave g, quad) owns cell g*4+quad of each group,
    //      16 lanes/cell, lane l15 covers h[k] for k = l15*4 .. l15*4+3 ----
    float wout4[4];
    #pragma unroll
    for (int e2 = 0; e2 < 4; ++e2) wout4[e2] = Wout[l15 * 4 + e2];
    const int od_c = g * 4 + quad;         // cell within group
    size_t ob[2];
    #pragma unroll
    for (int gx = 0; gx < 2; ++gx) {
        int cell = cell0 + gx * 16 + od_c;
        int b = cell / NN, n = cell - b * NN;
        ob[gx] = (size_t)b * FC * NN + n;
    }

    // ---- h0: fp32 regs + bf16 Abuf, both groups ----
    float hold0[4], hold1[4];
    #pragma unroll
    for (int rr = 0; rr < 4; ++rr) {
        int m0 = rowb + rr, m1 = 16 + rowb + rr;
        float h0 = hn0[((size_t)cell0 + m0) * HID + jcol];
        float h1 = hn0[((size_t)cell0 + m1) * HID + jcol];
        hold0[rr] = h0; hold1[rr] = h1;
        Abuf[m0 * AST + jcol] = f2bf(h0);
        Abuf[m1 * AST + jcol] = f2bf(h1);
    }
    __syncthreads();   // idxbuf / xbuf / Abuf ready

    // ---- stage Xt[0] (emb rows for t=0, both groups) ----
    const int r8 = tid >> 3, k4 = (tid & 7) * 4;
    {
        int idx = idxbuf[r8];
        float4 e4 = *(const float4*)(emb + (size_t)idx * EMBD + k4);
        *(uint2*)&Xt[0][r8 * XST + k4] =
            make_uint2(cvt_pk_bf16(e4.x, e4.y), cvt_pk_bf16(e4.z, e4.w));
    }
    __syncthreads();

    // ---- phase lambdas ----
    auto PHASE_A = [&](int X16, const unsigned short* Xc,
                       f32x4& ar, f32x4& az, f32x4& ani, f32x4& ang) {
        const bf16x8 a0 = *(const bf16x8*)&Abuf[(X16 + l15) * AST + quad * 8];
        const bf16x8 a1 = *(const bf16x8*)&Abuf[(X16 + l15) * AST + 32 + quad * 8];
        const bf16x8 x0 = *(const bf16x8*)&Xc[(X16 + l15) * XST + quad * 8];
        const f32x4 z4 = {0.f, 0.f, 0.f, 0.f};
        ar  = __builtin_amdgcn_mfma_f32_16x16x32_bf16(x0, BX[0], z4, 0, 0, 0);
        ar  = __builtin_amdgcn_mfma_f32_16x16x32_bf16(a0, Bf[0][0], ar, 0, 0, 0);
        ar  = __builtin_amdgcn_mfma_f32_16x16x32_bf16(a1, Bf[0][1], ar, 0, 0, 0);
        az  = __builtin_amdgcn_mfma_f32_16x16x32_bf16(x0, BX[1], z4, 0, 0, 0);
        az  = __builtin_amdgcn_mfma_f32_16x16x32_bf16(a0, Bf[1][0], az, 0, 0, 0);
        az  = __builtin_amdgcn_mfma_f32_16x16x32_bf16(a1, Bf[1][1], az, 0, 0, 0);
        ani = __builtin_amdgcn_mfma_f32_16x16x32_bf16(x0, BX[2], z4, 0, 0, 0);
        ang = __builtin_amdgcn_mfma_f32_16x16x32_bf16(a0, Bf[2][0], z4, 0, 0, 0);
        ang = __builtin_amdgcn_mfma_f32_16x16x32_bf16(a1, Bf[2][1], ang, 0, 0, 0);
    };

    auto PHASE_B = [&](int X16, f32x4& ar, f32x4& az, f32x4& ani, f32x4& ang,
                       float* hold) {
        #pragma unroll
        for (int rp = 0; rp < 2; ++rp) {
            float h2[2];
            #pragma unroll
            for (int k = 0; k < 2; ++k) {
                const int rr = rp * 2 + k;
                const int m  = X16 + rowb + rr;
                const float xp = xbuf[m];
                float sr = fmaf(w0r2, xp, ar[rr] + br2);
                float r  = __builtin_amdgcn_rcpf(1.0f + __builtin_amdgcn_exp2f(sr));
                float sz = fmaf(w0z2, xp, az[rr] + bz2);
                float z  = __builtin_amdgcn_rcpf(1.0f + __builtin_amdgcn_exp2f(sz));
                float v  = fmaf(r, ang[rr] + bhn2, fmaf(w0n2, xp, ani[rr] + bni2));
                float e  = __builtin_amdgcn_exp2f(v);   // saturates cleanly: no clamp
                float nv = fmaf(-2.0f, __builtin_amdgcn_rcpf(e + 1.0f), 1.0f);
                float hnew = fmaf(z, hold[rr] - nv, nv);
                hold[rr] = hnew;
                h2[k] = hnew;
            }
            unsigned pk = cvt_pk_bf16(h2[0], h2[1]);
            const int m0 = X16 + rowb + rp * 2;
            Abuf[m0 * AST + jcol]       = (unsigned short)pk;
            Abuf[(m0 + 1) * AST + jcol] = (unsigned short)(pk >> 16);
        }
    };

    // gx = GROUP INDEX (0/1); row offset and out base derived inside.
    // (R3 bug: call sites passed the group index into a row-offset param.)
    auto OUTDOT = [&](int gx, int tw, bool wr) {
        const int X16 = gx << 4;
        const uint2 hv = *(const uint2*)&Abuf[(X16 + od_c) * AST + l15 * 4];
        float o;
        o = wout4[0] * __builtin_bit_cast(float, hv.x << 16);
        o = fmaf(wout4[1], __builtin_bit_cast(float, hv.x & 0xFFFF0000u), o);
        o = fmaf(wout4[2], __builtin_bit_cast(float, hv.y << 16), o);
        o = fmaf(wout4[3], __builtin_bit_cast(float, hv.y & 0xFFFF0000u), o);
        o += __shfl_xor(o, 1);
        o += __shfl_xor(o, 2);
        o += __shfl_xor(o, 4);
        o += __shfl_xor(o, 8);
        if (l15 == 0) {
            float oo = o + bout0;
            out[ob[gx] + (size_t)tw * NN] = oo;
            if (wr) xbuf[X16 + od_c] = oo;
        }
    };

    f32x4 ar0, az0, ani0, ang0;   // group-0 accumulators (seg1 -> seg2)
    f32x4 ar1, az1, ani1, ang1;   // group-1 accumulators (seg2 -> next seg1)

    #pragma unroll 2
    for (int t = 0; t < FC; ++t) {
        // issue next-step emb gather EARLY; consumed at end of seg2
        const int tn = (t + 1 < FC) ? t + 1 : FC - 1;
        const int nidx = idxbuf[tn * CPB + r8];
        const float4 e4 = *(const float4*)(emb + (size_t)nidx * EMBD + k4);
        const unsigned short* Xc = Xt[t & 1];

        // ---- seg1: A(g0,t) ∥ B(g1,t-1) ∥ outdot(g0 -> out[t-1]) ----
        PHASE_A(0, Xc, ar0, az0, ani0, ang0);
        if (t > 0) {
            PHASE_B(16, ar1, az1, ani1, ang1, hold1);
            OUTDOT(0, t - 1, true);
        }
        lds_barrier();

        // ---- seg2: A(g1,t) ∥ B(g0,t) ∥ outdot(g1 -> out[t-1]) ----
        PHASE_A(16, Xc, ar1, az1, ani1, ang1);
        PHASE_B(0, ar0, az0, ani0, ang0, hold0);
        if (t > 0) OUTDOT(1, t - 1, true);
        // late half of the async stage: vmcnt wait lands here
        *(uint2*)&Xt[(t + 1) & 1][r8 * XST + k4] =
            make_uint2(cvt_pk_bf16(e4.x, e4.y), cvt_pk_bf16(e4.z, e4.w));
        lds_barrier();
    }

    // ---- epilogue: finish g1's last step, emit out[FC-1] for both ----
    PHASE_B(16, ar1, az1, ani1, ang1, hold1);
    OUTDOT(0, FC - 1, false);
    lds_barrier();
    OUTDOT(1, FC - 1, false);
}

extern "C" void kernel_launch(void* const* d_in, const int* in_sizes, int n_in,
                              void* d_out, int out_size, void* d_ws, size_t ws_size,
                              hipStream_t stream) {
    (void)in_sizes; (void)n_in; (void)out_size; (void)d_ws; (void)ws_size;
    const float* X    = (const float*)d_in[0];
    const float* hn   = (const float*)d_in[1];
    const float* xn   = (const float*)d_in[2];
    const float* emb  = (const float*)d_in[3];
    const float* Wih  = (const float*)d_in[4];
    const float* Whh  = (const float*)d_in[5];
    const float* bih  = (const float*)d_in[6];
    const float* bhh  = (const float*)d_in[7];
    const float* Wout = (const float*)d_in[8];
    const float* bout = (const float*)d_in[9];
    float* out = (float*)d_out;

    const int blocks = (BB * NN) / CPB;   // 2000
    gru_decoder<<<blocks, TPB, 0, stream>>>(X, hn, xn, emb, Wih, Whh,
                                            bih, bhh, Wout, bout, out);
}

// Round 5
// 268.830 us; speedup vs baseline: 1.0213x; 1.0213x over previous
//
#include <hip/hip_runtime.h>
#include <math.h>

// Problem constants
#define BB   64
#define FC   24
#define NN   1000
#define HID  64
#define EMBD 32
#define TT   48
#define FF   8
#define INSZ 33

// Decoder tiling: 16 cells per block, 4 waves, each wave owns 16 gate-cols
#define CPB  16
#define TPB  256
#define AST  72     // Hbuf stride in bf16 elems (144 B rows, 16B-aligned)
#define XST  40     // Xt stride in bf16 elems (80 B rows, 16B-aligned)

#define NL2E (-1.4426950408889634f)   // -log2(e): folded into r,z weights
#define TL2E ( 2.8853900817779268f)   // 2*log2(e): folded into n weights

typedef __attribute__((ext_vector_type(8))) short bf16x8;
typedef __attribute__((ext_vector_type(4))) float f32x4;

static __device__ __forceinline__ unsigned short f2bf(float f) {
    unsigned u = __builtin_bit_cast(unsigned, f);
    u += 0x7FFFu + ((u >> 16) & 1u);      // RNE
    return (unsigned short)(u >> 16);
}
// packed RNE f32->bf16: lo16 = bf16(a), hi16 = bf16(b)
static __device__ __forceinline__ unsigned cvt_pk_bf16(float a, float b) {
    unsigned r;
    asm("v_cvt_pk_bf16_f32 %0, %1, %2" : "=v"(r) : "v"(a), "v"(b));
    return r;
}
static __device__ __forceinline__ bf16x8 mk_bf8(float4 lo, float4 hi, float s) {
    union { unsigned u[4]; bf16x8 v; } r;
    r.u[0] = cvt_pk_bf16(lo.x * s, lo.y * s);
    r.u[1] = cvt_pk_bf16(lo.z * s, lo.w * s);
    r.u[2] = cvt_pk_bf16(hi.x * s, hi.y * s);
    r.u[3] = cvt_pk_bf16(hi.z * s, hi.w * s);
    return r.v;
}

// Barrier draining ONLY lgkmcnt (LDS). Safe: in-flight global ops are
// register loads (private) and `out` stores (never re-read in kernel).
static __device__ __forceinline__ void lds_barrier() {
    __builtin_amdgcn_sched_barrier(0);
    asm volatile("s_waitcnt lgkmcnt(0)" ::: "memory");
    __builtin_amdgcn_s_barrier();
    __builtin_amdgcn_sched_barrier(0);
}

__global__ __launch_bounds__(TPB) __attribute__((amdgpu_waves_per_eu(4)))
void gru_decoder(
    const float* __restrict__ X,    // [B][TT][N][F]
    const float* __restrict__ hn0,  // [B*N][HID]
    const float* __restrict__ xn,   // [B][N][1]
    const float* __restrict__ emb,  // [NEMB][EMBD]
    const float* __restrict__ Wih,  // [3*HID][INSZ]
    const float* __restrict__ Whh,  // [3*HID][HID]
    const float* __restrict__ bih,  // [3*HID]
    const float* __restrict__ bhh,  // [3*HID]
    const float* __restrict__ Wout, // [1][HID]
    const float* __restrict__ bout, // [1]
    float* __restrict__ out)        // [B][FC][N][1]
{
    __shared__ __align__(16) unsigned short Hbuf[2][CPB * AST]; // 4608 B
    __shared__ __align__(16) unsigned short Xt[2][CPB * XST];   // 2560 B
    __shared__ int   idxbuf[FC * CPB];                          // 1536 B
    __shared__ float xbuf0[CPB];                                // t=0 x only

    const int tid  = threadIdx.x;
    const int lane = tid & 63;
    const int g    = tid >> 6;         // wave 0..3, gate-cols g*16..g*16+15
    const int quad = lane >> 4;
    const int l15  = lane & 15;
    const int jcol = g * 16 + l15;
    const int rowb = quad * 4;
    const int cell0 = blockIdx.x * CPB;

    // ---- stage idx for all FC steps ----
    for (int e = tid; e < FC * CPB; e += TPB) {
        int t = e >> 4, m = e & 15;
        int cell = cell0 + m;
        int b = cell / NN, n = cell - b * NN;
        idxbuf[t * CPB + m] = (int)X[(((size_t)b * TT + t) * NN + n) * FF + 7];
    }
    if (tid < CPB) xbuf0[tid] = xn[cell0 + tid];

    // ---- persistent B fragments: Whh^T, log2e-prescaled (24 VGPRs) ----
    bf16x8 Bf[3][2];
    #pragma unroll
    for (int gate = 0; gate < 3; ++gate) {
        const float s = (gate < 2) ? NL2E : TL2E;
        #pragma unroll
        for (int ks = 0; ks < 2; ++ks) {
            const float* src = Whh + (size_t)(gate * HID + jcol) * HID + ks * 32 + quad * 8;
            Bf[gate][ks] = mk_bf8(*(const float4*)src, *(const float4*)(src + 4), s);
        }
    }
    // ---- Wih embedding-part fragments (cols 1..32), prescaled (12 VGPRs) ----
    bf16x8 BX[3];
    #pragma unroll
    for (int gate = 0; gate < 3; ++gate) {
        const float s = (gate < 2) ? NL2E : TL2E;
        const float* src = Wih + (size_t)(gate * HID + jcol) * INSZ + 1 + quad * 8;
        union { unsigned u[4]; bf16x8 v; } f;
        #pragma unroll
        for (int p = 0; p < 4; ++p)
            f.u[p] = cvt_pk_bf16(src[2 * p] * s, src[2 * p + 1] * s);
        BX[gate] = f.v;
    }
    // ---- Wout fragment, replicated to ALL 16 B-columns (8 VGPRs):
    //      every output column of the out-MFMA = h·Wout, so D[row][*]
    //      hands out(t-1) for row rowb+rr to the thread computing that
    //      row's gates — the x feedback stays in registers. ----
    bf16x8 BO[2];
    #pragma unroll
    for (int ks = 0; ks < 2; ++ks) {
        const float* src = Wout + ks * 32 + quad * 8;
        union { unsigned u[4]; bf16x8 v; } f;
        #pragma unroll
        for (int p = 0; p < 4; ++p)
            f.u[p] = cvt_pk_bf16(src[2 * p], src[2 * p + 1]);
        BO[ks] = f.v;
    }

    const float w0r2 = NL2E * Wih[(size_t)jcol * INSZ];
    const float w0z2 = NL2E * Wih[(size_t)(HID + jcol) * INSZ];
    const float w0n2 = TL2E * Wih[(size_t)(2 * HID + jcol) * INSZ];
    const float bout0 = bout[0];
    // biases with bout folded through w0 (x = ao + bout0 algebraically)
    const float br2p  = NL2E * (bih[jcol] + bhh[jcol]) + w0r2 * bout0;
    const float bz2p  = NL2E * (bih[HID + jcol] + bhh[HID + jcol]) + w0z2 * bout0;
    const float bni2p = TL2E * bih[2 * HID + jcol] + w0n2 * bout0;
    const float bhn2  = TL2E * bhh[2 * HID + jcol];

    // ---- out store bases: rows rowb+rr; only wave 0, l15==0 stores ----
    size_t sb[4];
    #pragma unroll
    for (int rr = 0; rr < 4; ++rr) {
        int cell = cell0 + rowb + rr;
        int b = cell / NN, n = cell - b * NN;
        sb[rr] = (size_t)b * FC * NN + n;
    }
    const bool storer = (g == 0) && (l15 == 0);

    // ---- h0: fp32 regs + bf16 Hbuf[0] ----
    float hold[4];
    #pragma unroll
    for (int rr = 0; rr < 4; ++rr) {
        int m = rowb + rr;
        float h = hn0[((size_t)cell0 + m) * HID + jcol];
        hold[rr] = h;
        Hbuf[0][m * AST + jcol] = f2bf(h);
    }
    __syncthreads();   // idxbuf / xbuf0 / Hbuf[0] ready

    // ---- stage Xt[0] (emb rows for t=0): 128 threads, 16 rows x 8 kquads ----
    const int r8 = tid >> 3, k4 = (tid & 7) * 4;
    const bool stg = tid < CPB * 8;    // waves 0,1
    if (stg) {
        int idx = idxbuf[r8];
        float4 e4 = *(const float4*)(emb + (size_t)idx * EMBD + k4);
        *(uint2*)&Xt[0][r8 * XST + k4] =
            make_uint2(cvt_pk_bf16(e4.x, e4.y), cvt_pk_bf16(e4.z, e4.w));
    }
    __syncthreads();

    f32x4 ar, az, ani, ang, ao;

    auto PHASE_A = [&](const unsigned short* Hb, const unsigned short* Xc) {
        const bf16x8 a0 = *(const bf16x8*)&Hb[l15 * AST + quad * 8];
        const bf16x8 a1 = *(const bf16x8*)&Hb[l15 * AST + 32 + quad * 8];
        const bf16x8 x0 = *(const bf16x8*)&Xc[l15 * XST + quad * 8];
        const f32x4 z4 = {0.f, 0.f, 0.f, 0.f};
        ar  = __builtin_amdgcn_mfma_f32_16x16x32_bf16(x0, BX[0], z4, 0, 0, 0);
        ar  = __builtin_amdgcn_mfma_f32_16x16x32_bf16(a0, Bf[0][0], ar, 0, 0, 0);
        ar  = __builtin_amdgcn_mfma_f32_16x16x32_bf16(a1, Bf[0][1], ar, 0, 0, 0);
        az  = __builtin_amdgcn_mfma_f32_16x16x32_bf16(x0, BX[1], z4, 0, 0, 0);
        az  = __builtin_amdgcn_mfma_f32_16x16x32_bf16(a0, Bf[1][0], az, 0, 0, 0);
        az  = __builtin_amdgcn_mfma_f32_16x16x32_bf16(a1, Bf[1][1], az, 0, 0, 0);
        ani = __builtin_amdgcn_mfma_f32_16x16x32_bf16(x0, BX[2], z4, 0, 0, 0);
        ang = __builtin_amdgcn_mfma_f32_16x16x32_bf16(a0, Bf[2][0], z4, 0, 0, 0);
        ang = __builtin_amdgcn_mfma_f32_16x16x32_bf16(a1, Bf[2][1], ang, 0, 0, 0);
        ao  = __builtin_amdgcn_mfma_f32_16x16x32_bf16(a0, BO[0], z4, 0, 0, 0);
        ao  = __builtin_amdgcn_mfma_f32_16x16x32_bf16(a1, BO[1], ao, 0, 0, 0);
    };

    auto GATES = [&](int rr, float xv) -> float {
        float sr = fmaf(w0r2, xv, ar[rr] + br2p);
        float r  = __builtin_amdgcn_rcpf(1.0f + __builtin_amdgcn_exp2f(sr));
        float sz = fmaf(w0z2, xv, az[rr] + bz2p);
        float z  = __builtin_amdgcn_rcpf(1.0f + __builtin_amdgcn_exp2f(sz));
        float v  = fmaf(r, ang[rr] + bhn2, fmaf(w0n2, xv, ani[rr] + bni2p));
        float e  = __builtin_amdgcn_exp2f(v);   // saturates cleanly: no clamp
        float nv = fmaf(-2.0f, __builtin_amdgcn_rcpf(e + 1.0f), 1.0f);
        float hnew = fmaf(z, hold[rr] - nv, nv);
        hold[rr] = hnew;
        return hnew;
    };

    auto WRITE_H = [&](unsigned short* Hw, int rp, float h0, float h1) {
        unsigned pk = cvt_pk_bf16(h0, h1);
        const int m0 = rowb + rp * 2;
        Hw[m0 * AST + jcol]       = (unsigned short)pk;
        Hw[(m0 + 1) * AST + jcol] = (unsigned short)(pk >> 16);
    };

    // ---- peeled t=0: x comes from xn (xbuf0), no out store ----
    {
        float4 e4 = {0.f, 0.f, 0.f, 0.f};
        if (stg) {
            int idx = idxbuf[1 * CPB + r8];
            e4 = *(const float4*)(emb + (size_t)idx * EMBD + k4);
        }
        PHASE_A(Hbuf[0], Xt[0]);
        #pragma unroll
        for (int rp = 0; rp < 2; ++rp) {
            float h0 = GATES(rp * 2,     xbuf0[rowb + rp * 2]     - bout0);
            float h1 = GATES(rp * 2 + 1, xbuf0[rowb + rp * 2 + 1] - bout0);
            WRITE_H(Hbuf[1], rp, h0, h1);
        }
        if (stg)
            *(uint2*)&Xt[1][r8 * XST + k4] =
                make_uint2(cvt_pk_bf16(e4.x, e4.y), cvt_pk_bf16(e4.z, e4.w));
        lds_barrier();
    }

    // ---- main loop: ONE barrier per step; x feedback via ao registers ----
    #pragma unroll 2
    for (int t = 1; t < FC; ++t) {
        const int tn = (t + 1 < FC) ? t + 1 : FC - 1;
        float4 e4 = {0.f, 0.f, 0.f, 0.f};
        if (stg)
            e4 = *(const float4*)(emb + (size_t)idxbuf[tn * CPB + r8] * EMBD + k4);

        PHASE_A(Hbuf[t & 1], Xt[t & 1]);   // gates + out(t-1), all from LDS+regs

        unsigned short* Hw = Hbuf[(t + 1) & 1];
        #pragma unroll
        for (int rp = 0; rp < 2; ++rp) {
            float h0 = GATES(rp * 2,     ao[rp * 2]);
            float h1 = GATES(rp * 2 + 1, ao[rp * 2 + 1]);
            WRITE_H(Hw, rp, h0, h1);
        }
        if (storer) {
            #pragma unroll
            for (int rr = 0; rr < 4; ++rr)
                out[sb[rr] + (size_t)(t - 1) * NN] = ao[rr] + bout0;
        }
        if (stg)
            *(uint2*)&Xt[(t + 1) & 1][r8 * XST + k4] =
                make_uint2(cvt_pk_bf16(e4.x, e4.y), cvt_pk_bf16(e4.z, e4.w));
        lds_barrier();
    }

    // ---- epilogue: out(FC-1) from h(FC-1) in Hbuf[FC&1] ----
    {
        const unsigned short* Hb = Hbuf[FC & 1];
        const bf16x8 a0 = *(const bf16x8*)&Hb[l15 * AST + quad * 8];
        const bf16x8 a1 = *(const bf16x8*)&Hb[l15 * AST + 32 + quad * 8];
        const f32x4 z4 = {0.f, 0.f, 0.f, 0.f};
        f32x4 o = __builtin_amdgcn_mfma_f32_16x16x32_bf16(a0, BO[0], z4, 0, 0, 0);
        o = __builtin_amdgcn_mfma_f32_16x16x32_bf16(a1, BO[1], o, 0, 0, 0);
        if (storer) {
            #pragma unroll
            for (int rr = 0; rr < 4; ++rr)
                out[sb[rr] + (size_t)(FC - 1) * NN] = o[rr] + bout0;
        }
    }
}

extern "C" void kernel_launch(void* const* d_in, const int* in_sizes, int n_in,
                              void* d_out, int out_size, void* d_ws, size_t ws_size,
                              hipStream_t stream) {
    (void)in_sizes; (void)n_in; (void)out_size; (void)d_ws; (void)ws_size;
    const float* X    = (const float*)d_in[0];
    const float* hn   = (const float*)d_in[1];
    const float* xn   = (const float*)d_in[2];
    const float* emb  = (const float*)d_in[3];
    const float* Wih  = (const float*)d_in[4];
    const float* Whh  = (const float*)d_in[5];
    const float* bih  = (const float*)d_in[6];
    const float* bhh  = (const float*)d_in[7];
    const float* Wout = (const float*)d_in[8];
    const float* bout = (const float*)d_in[9];
    float* out = (float*)d_out;

    const int blocks = (BB * NN) / CPB;   // 4000
    gru_decoder<<<blocks, TPB, 0, stream>>>(X, hn, xn, emb, Wih, Whh,
                                            bih, bhh, Wout, bout, out);
}

// Round 6
// 259.267 us; speedup vs baseline: 1.0590x; 1.0369x over previous
//
#include <hip/hip_runtime.h>
#include <math.h>

// Problem constants
#define BB   64
#define FC   24
#define NN   1000
#define HID  64
#define EMBD 32
#define TT   48
#define FF   8
#define INSZ 33

// Decoder tiling: 16 cells per block, 4 waves, each wave owns 16 gate-cols
#define CPB  16
#define TPB  256
#define AST  72     // Hbuf stride in bf16 elems (144 B rows, 16B-aligned)
#define XST  40     // Xt stride in bf16 elems (80 B rows, 16B-aligned)

#define NL2E (-1.4426950408889634f)   // -log2(e): folded into r,z weights
#define TL2E ( 2.8853900817779268f)   // 2*log2(e): folded into n weights

typedef __attribute__((ext_vector_type(8))) short bf16x8;
typedef __attribute__((ext_vector_type(4))) float f32x4;

static __device__ __forceinline__ unsigned short f2bf(float f) {
    unsigned u = __builtin_bit_cast(unsigned, f);
    u += 0x7FFFu + ((u >> 16) & 1u);      // RNE
    return (unsigned short)(u >> 16);
}
// packed RNE f32->bf16: lo16 = bf16(a), hi16 = bf16(b)
static __device__ __forceinline__ unsigned cvt_pk_bf16(float a, float b) {
    unsigned r;
    asm("v_cvt_pk_bf16_f32 %0, %1, %2" : "=v"(r) : "v"(a), "v"(b));
    return r;
}
static __device__ __forceinline__ bf16x8 mk_bf8(float4 lo, float4 hi, float s) {
    union { unsigned u[4]; bf16x8 v; } r;
    r.u[0] = cvt_pk_bf16(lo.x * s, lo.y * s);
    r.u[1] = cvt_pk_bf16(lo.z * s, lo.w * s);
    r.u[2] = cvt_pk_bf16(hi.x * s, hi.y * s);
    r.u[3] = cvt_pk_bf16(hi.z * s, hi.w * s);
    return r.v;
}

// Barrier draining ONLY lgkmcnt (LDS). Safe: in-flight global ops are
// register loads (private) and `out` stores (never re-read in kernel).
static __device__ __forceinline__ void lds_barrier() {
    __builtin_amdgcn_sched_barrier(0);
    asm volatile("s_waitcnt lgkmcnt(0)" ::: "memory");
    __builtin_amdgcn_s_barrier();
    __builtin_amdgcn_sched_barrier(0);
}

__global__ __launch_bounds__(TPB) __attribute__((amdgpu_waves_per_eu(4)))
void gru_decoder(
    const float* __restrict__ X,    // [B][TT][N][F]
    const float* __restrict__ hn0,  // [B*N][HID]
    const float* __restrict__ xn,   // [B][N][1]
    const float* __restrict__ emb,  // [NEMB][EMBD]
    const float* __restrict__ Wih,  // [3*HID][INSZ]
    const float* __restrict__ Whh,  // [3*HID][HID]
    const float* __restrict__ bih,  // [3*HID]
    const float* __restrict__ bhh,  // [3*HID]
    const float* __restrict__ Wout, // [1][HID]
    const float* __restrict__ bout, // [1]
    float* __restrict__ out)        // [B][FC][N][1]
{
    __shared__ __align__(16) unsigned short Hbuf[2][CPB * AST]; // 4608 B
    __shared__ __align__(16) unsigned short Xt[2][CPB * XST];   // 2560 B
    __shared__ int   idxbuf[(FC + 1) * CPB];                    // 1600 B
    __shared__ float xbuf0[CPB];                                // t=0 x only

    const int tid  = threadIdx.x;
    const int lane = tid & 63;
    const int g    = tid >> 6;         // wave 0..3, gate-cols g*16..g*16+15
    const int quad = lane >> 4;
    const int l15  = lane & 15;
    const int jcol = g * 16 + l15;
    const int rowb = quad * 4;
    const int cell0 = blockIdx.x * CPB;

    // ---- stage idx for steps 0..FC (row FC duplicates FC-1: no clamp in loop) ----
    for (int e = tid; e < (FC + 1) * CPB; e += TPB) {
        int t = e >> 4, m = e & 15;
        int tt = (t < FC) ? t : FC - 1;
        int cell = cell0 + m;
        int b = cell / NN, n = cell - b * NN;
        idxbuf[e] = (int)X[(((size_t)b * TT + tt) * NN + n) * FF + 7];
    }
    if (tid < CPB) xbuf0[tid] = xn[cell0 + tid];

    const float bout0 = bout[0];
    const float w0r2 = NL2E * Wih[(size_t)jcol * INSZ];
    const float w0z2 = NL2E * Wih[(size_t)(HID + jcol) * INSZ];
    const float w0n2 = TL2E * Wih[(size_t)(2 * HID + jcol) * INSZ];
    // raw w0 for the r,z rank-1 fold (pre-prescale scale)
    const float w0r = Wih[(size_t)jcol * INSZ];
    const float w0z = Wih[(size_t)(HID + jcol) * INSZ];

    // ---- persistent B fragments: Whh^T, log2e-prescaled; r,z gates get
    //      the rank-1 fold  Whh_eff = Whh + w0 ⊗ wout  (x-feedback enters
    //      the matmul; n-gate excluded: its x-term is outside r*h_n). ----
    bf16x8 Bf[3][2];
    #pragma unroll
    for (int gate = 0; gate < 3; ++gate) {
        const float s  = (gate < 2) ? NL2E : TL2E;
        const float wf = (gate == 0) ? w0r : (gate == 1) ? w0z : 0.0f;
        #pragma unroll
        for (int ks = 0; ks < 2; ++ks) {
            const float* src = Whh + (size_t)(gate * HID + jcol) * HID + ks * 32 + quad * 8;
            const float* wo  = Wout + ks * 32 + quad * 8;
            float4 lo = *(const float4*)src;
            float4 hi = *(const float4*)(src + 4);
            float4 wl = *(const float4*)wo;
            float4 wh = *(const float4*)(wo + 4);
            lo.x = fmaf(wf, wl.x, lo.x); lo.y = fmaf(wf, wl.y, lo.y);
            lo.z = fmaf(wf, wl.z, lo.z); lo.w = fmaf(wf, wl.w, lo.w);
            hi.x = fmaf(wf, wh.x, hi.x); hi.y = fmaf(wf, wh.y, hi.y);
            hi.z = fmaf(wf, wh.z, hi.z); hi.w = fmaf(wf, wh.w, hi.w);
            Bf[gate][ks] = mk_bf8(lo, hi, s);
        }
    }
    // ---- Wih embedding-part fragments (cols 1..32), prescaled (12 VGPRs) ----
    bf16x8 BX[3];
    #pragma unroll
    for (int gate = 0; gate < 3; ++gate) {
        const float s = (gate < 2) ? NL2E : TL2E;
        const float* src = Wih + (size_t)(gate * HID + jcol) * INSZ + 1 + quad * 8;
        union { unsigned u[4]; bf16x8 v; } f;
        #pragma unroll
        for (int p = 0; p < 4; ++p)
            f.u[p] = cvt_pk_bf16(src[2 * p] * s, src[2 * p + 1] * s);
        BX[gate] = f.v;
    }
    // ---- Wout fragment, replicated to all 16 B-cols (8 VGPRs): ao = h·wout ----
    bf16x8 BO[2];
    #pragma unroll
    for (int ks = 0; ks < 2; ++ks) {
        const float* src = Wout + ks * 32 + quad * 8;
        union { unsigned u[4]; bf16x8 v; } f;
        #pragma unroll
        for (int p = 0; p < 4; ++p)
            f.u[p] = cvt_pk_bf16(src[2 * p], src[2 * p + 1]);
        BO[ks] = f.v;
    }

    // biases (incl. w0*bout fold) as MFMA C operands — loop-invariant
    const float br2p  = NL2E * (bih[jcol] + bhh[jcol]) + w0r2 * bout0;
    const float bz2p  = NL2E * (bih[HID + jcol] + bhh[HID + jcol]) + w0z2 * bout0;
    const float bni2p = TL2E * bih[2 * HID + jcol] + w0n2 * bout0;
    const float bhn2  = TL2E * bhh[2 * HID + jcol];
    const f32x4 cr  = {br2p,  br2p,  br2p,  br2p };
    const f32x4 cz  = {bz2p,  bz2p,  bz2p,  bz2p };
    const f32x4 cni = {bni2p, bni2p, bni2p, bni2p};
    const f32x4 cng = {bhn2,  bhn2,  bhn2,  bhn2 };

    // ---- out store bases: rows rowb+rr; only wave 0, l15==0 stores ----
    size_t sb[4];
    #pragma unroll
    for (int rr = 0; rr < 4; ++rr) {
        int cell = cell0 + rowb + rr;
        int b = cell / NN, n = cell - b * NN;
        sb[rr] = (size_t)b * FC * NN + n;
    }
    const bool storer = (g == 0) && (l15 == 0);

    // ---- h0: fp32 regs + bf16 Hbuf[0] ----
    float hold[4];
    #pragma unroll
    for (int rr = 0; rr < 4; ++rr) {
        int m = rowb + rr;
        float h = hn0[((size_t)cell0 + m) * HID + jcol];
        hold[rr] = h;
        Hbuf[0][m * AST + jcol] = f2bf(h);
    }
    __syncthreads();   // idxbuf / xbuf0 / Hbuf[0] ready

    // ---- stage Xt[0]: 128 threads, 16 rows x 8 k-quads ----
    const int r8 = tid >> 3, k4 = (tid & 7) * 4;
    const bool stg = tid < CPB * 8;    // waves 0,1
    if (stg) {
        int idx = idxbuf[r8];
        float4 e4 = *(const float4*)(emb + (size_t)idx * EMBD + k4);
        *(uint2*)&Xt[0][r8 * XST + k4] =
            make_uint2(cvt_pk_bf16(e4.x, e4.y), cvt_pk_bf16(e4.z, e4.w));
    }
    __syncthreads();

    f32x4 ar, az, ani, ang, ao;

    auto PHASE_A = [&](const unsigned short* Hb, const unsigned short* Xc) {
        const bf16x8 a0 = *(const bf16x8*)&Hb[l15 * AST + quad * 8];
        const bf16x8 a1 = *(const bf16x8*)&Hb[l15 * AST + 32 + quad * 8];
        const bf16x8 x0 = *(const bf16x8*)&Xc[l15 * XST + quad * 8];
        const f32x4 z4 = {0.f, 0.f, 0.f, 0.f};
        ar  = __builtin_amdgcn_mfma_f32_16x16x32_bf16(x0, BX[0], cr, 0, 0, 0);
        ar  = __builtin_amdgcn_mfma_f32_16x16x32_bf16(a0, Bf[0][0], ar, 0, 0, 0);
        ar  = __builtin_amdgcn_mfma_f32_16x16x32_bf16(a1, Bf[0][1], ar, 0, 0, 0);
        az  = __builtin_amdgcn_mfma_f32_16x16x32_bf16(x0, BX[1], cz, 0, 0, 0);
        az  = __builtin_amdgcn_mfma_f32_16x16x32_bf16(a0, Bf[1][0], az, 0, 0, 0);
        az  = __builtin_amdgcn_mfma_f32_16x16x32_bf16(a1, Bf[1][1], az, 0, 0, 0);
        ani = __builtin_amdgcn_mfma_f32_16x16x32_bf16(x0, BX[2], cni, 0, 0, 0);
        ang = __builtin_amdgcn_mfma_f32_16x16x32_bf16(a0, Bf[2][0], cng, 0, 0, 0);
        ang = __builtin_amdgcn_mfma_f32_16x16x32_bf16(a1, Bf[2][1], ang, 0, 0, 0);
        ao  = __builtin_amdgcn_mfma_f32_16x16x32_bf16(a0, BO[0], z4, 0, 0, 0);
        ao  = __builtin_amdgcn_mfma_f32_16x16x32_bf16(a1, BO[1], ao, 0, 0, 0);
    };

    // main-loop gates: x-feedback fully in the accumulators (r,z) or one
    // fma off ao (n). 8 full-rate + 3 trans ops per element.
    auto GATES = [&](int rr) -> float {
        float r  = __builtin_amdgcn_rcpf(1.0f + __builtin_amdgcn_exp2f(ar[rr]));
        float z  = __builtin_amdgcn_rcpf(1.0f + __builtin_amdgcn_exp2f(az[rr]));
        float v  = fmaf(r, ang[rr], fmaf(w0n2, ao[rr], ani[rr]));
        float e  = __builtin_amdgcn_exp2f(v);   // saturates cleanly: no clamp
        float nv = fmaf(-2.0f, __builtin_amdgcn_rcpf(e + 1.0f), 1.0f);
        float hnew = fmaf(z, hold[rr] - nv, nv);
        hold[rr] = hnew;
        return hnew;
    };
    // peel (t=0): real x comes from xn; correct the folded rank-1 term
    auto GATES0 = [&](int rr, float x0v) -> float {
        float xc = x0v - bout0 - ao[rr];        // r,z fold correction
        float xn_ = x0v - bout0;                // n-gate x (bias holds w0n*bout)
        float r  = __builtin_amdgcn_rcpf(1.0f + __builtin_amdgcn_exp2f(fmaf(w0r2, xc, ar[rr])));
        float z  = __builtin_amdgcn_rcpf(1.0f + __builtin_amdgcn_exp2f(fmaf(w0z2, xc, az[rr])));
        float v  = fmaf(r, ang[rr], fmaf(w0n2, xn_, ani[rr]));
        float e  = __builtin_amdgcn_exp2f(v);
        float nv = fmaf(-2.0f, __builtin_amdgcn_rcpf(e + 1.0f), 1.0f);
        float hnew = fmaf(z, hold[rr] - nv, nv);
        hold[rr] = hnew;
        return hnew;
    };

    auto WRITE_H = [&](unsigned short* Hw, int rp, float h0, float h1) {
        unsigned pk = cvt_pk_bf16(h0, h1);
        const int m0 = rowb + rp * 2;
        Hw[m0 * AST + jcol]       = (unsigned short)pk;
        Hw[(m0 + 1) * AST + jcol] = (unsigned short)(pk >> 16);
    };

    // ---- peeled t=0 ----
    {
        float4 e4 = {0.f, 0.f, 0.f, 0.f};
        if (stg) {
            int idx = idxbuf[1 * CPB + r8];
            e4 = *(const float4*)(emb + (size_t)idx * EMBD + k4);
        }
        PHASE_A(Hbuf[0], Xt[0]);
        #pragma unroll
        for (int rp = 0; rp < 2; ++rp) {
            float h0 = GATES0(rp * 2,     xbuf0[rowb + rp * 2]);
            float h1 = GATES0(rp * 2 + 1, xbuf0[rowb + rp * 2 + 1]);
            WRITE_H(Hbuf[1], rp, h0, h1);
        }
        if (stg)
            *(uint2*)&Xt[1][r8 * XST + k4] =
                make_uint2(cvt_pk_bf16(e4.x, e4.y), cvt_pk_bf16(e4.z, e4.w));
        lds_barrier();
    }

    // ---- main loop: ONE barrier per step; x feedback inside the MFMAs ----
    #pragma unroll 2
    for (int t = 1; t < FC; ++t) {
        float4 e4 = {0.f, 0.f, 0.f, 0.f};
        if (stg)
            e4 = *(const float4*)(emb + (size_t)idxbuf[(t + 1) * CPB + r8] * EMBD + k4);

        PHASE_A(Hbuf[t & 1], Xt[t & 1]);

        unsigned short* Hw = Hbuf[(t + 1) & 1];
        #pragma unroll
        for (int rp = 0; rp < 2; ++rp) {
            float h0 = GATES(rp * 2);
            float h1 = GATES(rp * 2 + 1);
            WRITE_H(Hw, rp, h0, h1);
        }
        if (storer) {
            #pragma unroll
            for (int rr = 0; rr < 4; ++rr)
                out[sb[rr] + (size_t)(t - 1) * NN] = ao[rr] + bout0;
        }
        if (stg)
            *(uint2*)&Xt[(t + 1) & 1][r8 * XST + k4] =
                make_uint2(cvt_pk_bf16(e4.x, e4.y), cvt_pk_bf16(e4.z, e4.w));
        lds_barrier();
    }

    // ---- epilogue: out(FC-1) from h(FC-1) in Hbuf[FC&1] ----
    {
        const unsigned short* Hb = Hbuf[FC & 1];
        const bf16x8 a0 = *(const bf16x8*)&Hb[l15 * AST + quad * 8];
        const bf16x8 a1 = *(const bf16x8*)&Hb[l15 * AST + 32 + quad * 8];
        const f32x4 z4 = {0.f, 0.f, 0.f, 0.f};
        f32x4 o = __builtin_amdgcn_mfma_f32_16x16x32_bf16(a0, BO[0], z4, 0, 0, 0);
        o = __builtin_amdgcn_mfma_f32_16x16x32_bf16(a1, BO[1], o, 0, 0, 0);
        if (storer) {
            #pragma unroll
            for (int rr = 0; rr < 4; ++rr)
                out[sb[rr] + (size_t)(FC - 1) * NN] = o[rr] + bout0;
        }
    }
}

extern "C" void kernel_launch(void* const* d_in, const int* in_sizes, int n_in,
                              void* d_out, int out_size, void* d_ws, size_t ws_size,
                              hipStream_t stream) {
    (void)in_sizes; (void)n_in; (void)out_size; (void)d_ws; (void)ws_size;
    const float* X    = (const float*)d_in[0];
    const float* hn   = (const float*)d_in[1];
    const float* xn   = (const float*)d_in[2];
    const float* emb  = (const float*)d_in[3];
    const float* Wih  = (const float*)d_in[4];
    const float* Whh  = (const float*)d_in[5];
    const float* bih  = (const float*)d_in[6];
    const float* bhh  = (const float*)d_in[7];
    const float* Wout = (const float*)d_in[8];
    const float* bout = (const float*)d_in[9];
    float* out = (float*)d_out;

    const int blocks = (BB * NN) / CPB;   // 4000
    gru_decoder<<<blocks, TPB, 0, stream>>>(X, hn, xn, emb, Wih, Whh,
                                            bih, bhh, Wout, bout, out);
}